// Round 2
// baseline (658.333 us; speedup 1.0000x reference)
//
#include <hip/hip_runtime.h>
#include <math.h>

// B=131072 rows, C=1000 classes fp32. out = mean(2 - 2*softmax(x)[i,tgt[i]]).
// One wave per row-group: 4 rows/wave, ALL loads (16x float4 row data +
// 4 target gathers + 4 tgt indices) issued up-front for max MLP; no
// dependent-load chains inside the row loop. Target gather is wave-uniform
// (HW broadcast) so p_t is computed redundantly by all lanes -- no
// exec-masked lane0 stall. Two-stage reduction through d_ws.

constexpr int C_CLS = 1000;
constexpr int NV4 = C_CLS / 4;             // 250 float4 per row
constexpr int WAVES_PER_BLOCK = 4;         // 256 threads
constexpr int ROWS_PER_WAVE = 4;           // B (131072) % 16 == 0 -> no row guards
constexpr int ROWS_PER_BLOCK = WAVES_PER_BLOCK * ROWS_PER_WAVE;  // 16

__global__ __launch_bounds__(256) void softmax_gather_kernel(
    const float* __restrict__ x, const int* __restrict__ tgt,
    float* __restrict__ partials, int B)
{
    const int lane = threadIdx.x & 63;
    const int wave = threadIdx.x >> 6;
    const int row0 = blockIdx.x * ROWS_PER_BLOCK + wave * ROWS_PER_WAVE;

    // Target indices first (wave-uniform loads -> broadcast), so the gather
    // addresses are ready when we issue the bulk loads.
    int t[ROWS_PER_WAVE];
    #pragma unroll
    for (int r = 0; r < ROWS_PER_WAVE; ++r) t[r] = tgt[row0 + r];

    // Issue everything: 16 coalesced float4 (1 KiB/wave each) + 4 uniform
    // gathers. ~16.3 KB in flight per wave.
    float4 v[ROWS_PER_WAVE][4];
    float xt[ROWS_PER_WAVE];
    #pragma unroll
    for (int r = 0; r < ROWS_PER_WAVE; ++r) {
        const float4* rp = reinterpret_cast<const float4*>(x + (size_t)(row0 + r) * C_CLS);
        #pragma unroll
        for (int k = 0; k < 4; ++k) {
            const int idx = lane + 64 * k;
            if (idx < NV4) {
                v[r][k] = rp[idx];
            } else {
                v[r][k] = make_float4(-INFINITY, -INFINITY, -INFINITY, -INFINITY);
            }
        }
        xt[r] = x[(size_t)(row0 + r) * C_CLS + t[r]];
    }

    float pacc = 0.0f;  // uniform across lanes after the butterflies
    #pragma unroll
    for (int r = 0; r < ROWS_PER_WAVE; ++r) {
        float m = -INFINITY;
        #pragma unroll
        for (int k = 0; k < 4; ++k)
            m = fmaxf(m, fmaxf(fmaxf(v[r][k].x, v[r][k].y), fmaxf(v[r][k].z, v[r][k].w)));
        #pragma unroll
        for (int off = 32; off > 0; off >>= 1)
            m = fmaxf(m, __shfl_xor(m, off));

        float s = 0.0f;   // exp(-INF - m) == 0 for the 6 padded lanes in k=3
        #pragma unroll
        for (int k = 0; k < 4; ++k)
            s += __expf(v[r][k].x - m) + __expf(v[r][k].y - m)
               + __expf(v[r][k].z - m) + __expf(v[r][k].w - m);
        #pragma unroll
        for (int off = 32; off > 0; off >>= 1)
            s += __shfl_xor(s, off);

        pacc += __expf(xt[r] - m) / s;
    }

    __shared__ float sm[WAVES_PER_BLOCK];
    if (lane == 0) sm[wave] = pacc;
    __syncthreads();
    if (threadIdx.x == 0)
        partials[blockIdx.x] = sm[0] + sm[1] + sm[2] + sm[3];
}

__global__ __launch_bounds__(1024) void finalize_kernel(
    const float* __restrict__ partials, int n, float* __restrict__ out, float invB)
{
    float s = 0.0f;
    for (int i = threadIdx.x; i < n; i += 1024) s += partials[i];
    #pragma unroll
    for (int off = 32; off > 0; off >>= 1) s += __shfl_xor(s, off);

    __shared__ float sm[16];
    const int lane = threadIdx.x & 63;
    const int wave = threadIdx.x >> 6;
    if (lane == 0) sm[wave] = s;
    __syncthreads();
    if (threadIdx.x == 0) {
        float t = 0.0f;
        #pragma unroll
        for (int w = 0; w < 16; ++w) t += sm[w];
        out[0] = 2.0f - 2.0f * t * invB;
    }
}

extern "C" void kernel_launch(void* const* d_in, const int* in_sizes, int n_in,
                              void* d_out, int out_size, void* d_ws, size_t ws_size,
                              hipStream_t stream)
{
    const float* x   = (const float*)d_in[0];
    const int*   tgt = (const int*)d_in[1];
    float*       out = (float*)d_out;
    float*       partials = (float*)d_ws;

    const int B = in_sizes[1];                                   // 131072
    const int grid = (B + ROWS_PER_BLOCK - 1) / ROWS_PER_BLOCK;  // 8192

    softmax_gather_kernel<<<grid, 256, 0, stream>>>(x, tgt, partials, B);
    finalize_kernel<<<1, 1024, 0, stream>>>(partials, grid, out, 1.0f / (float)B);
}